// Round 11
// baseline (144.125 us; speedup 1.0000x reference)
//
#include <hip/hip_runtime.h>

#define VOCAB 50257
#define EMBED 512
#define HID   512
#define B     128
#define SRC   128
#define NT393 393        // fc1 column tiles of 128
#define WPKG  3142       // 16-col groups in packed W (= ceil(50257/16))

typedef __attribute__((ext_vector_type(8))) short short8;
typedef __attribute__((ext_vector_type(4))) float f32x4;

// f32 -> bf16 (round-to-nearest-even), result in low 16 bits
__device__ __forceinline__ unsigned f2bf(float x) {
    unsigned u = __builtin_bit_cast(unsigned, x);
    return (u + 0x7fffu + ((u >> 16) & 1u)) >> 16;
}
__device__ __forceinline__ unsigned pk2(float lo, float hi) {
    return f2bf(lo) | (f2bf(hi) << 16);
}
__device__ __forceinline__ uint4 pk8(const float* p) {
    uint4 r;
    r.x = pk2(p[0], p[1]); r.y = pk2(p[2], p[3]);
    r.z = pk2(p[4], p[5]); r.w = pk2(p[6], p[7]);
    return r;
}
__device__ __forceinline__ uint4 pk8v(float4 a, float4 b) {
    uint4 r;
    r.x = pk2(a.x, a.y); r.y = pk2(a.z, a.w);
    r.z = pk2(b.x, b.y); r.w = pk2(b.z, b.w);
    return r;
}
__device__ __forceinline__ void gll16(const void* g, void* l) {
    __builtin_amdgcn_global_load_lds(
        (const __attribute__((address_space(1))) void*)g,
        (__attribute__((address_space(3))) void*)l, 16, 0, 0);
}

// Fragment-packed A layout (bf16, mfma_f32_16x16x32_bf16 A-operand order):
// uint4 index = ((kc*8 + mt)*4 + ksl)*64 + kg*16 + (row&15)

// Packed-W layout (B-operand frags): for col n, k-octet ko (k=ko*8):
//   wpk[(n>>4)*1024 + ko*16 + (n&15)]
// fc1w wave (16 cols) reads slice ks as 64 CONSECUTIVE uint4 (1KB).

// ---------------------------------------------------------------------------
// K0: DEDICATED W-conversion kernel (pure stream, no LDS, high occupancy).
// Per wave one 16-col group: 16 iters of {4 rows x 512B contiguous read,
// 16 x 64B full-line writes}. Math identical to r10's verified wconv_wave.
// ---------------------------------------------------------------------------
__global__ __launch_bounds__(256) void k_wconv(const float* __restrict__ fw,
                                               uint4* __restrict__ wpk) {
    const int lane = threadIdx.x & 63;
    const int gw = blockIdx.x * 4 + (threadIdx.x >> 6);
    const int gstride = gridDim.x * 4;
    const float4* fw4 = (const float4*)fw;
    for (int g = gw; g < WPKG; g += gstride) {
#pragma unroll
        for (int oj = 0; oj < 16; ++oj) {
            const int oc = oj >> 2, j = oj & 3;
            int r = g * 16 + j * 4 + (lane & 3);
            int rc = r < VOCAB ? r : VOCAB - 1;
            const int ko = oc * 16 + (lane >> 2);
            const float4* src = fw4 + (size_t)rc * 128 + ko * 2;
            wpk[(size_t)g * 1024 + ko * 16 + j * 4 + (lane & 3)] =
                pk8v(src[0], src[1]);
        }
    }
}

// ---------------------------------------------------------------------------
// K1: pack rnn_in = [emb(x[b]) | ctxv[b]]  (K=1024) and h0[b]  (K=512)
// ---------------------------------------------------------------------------
__global__ void k_embed_pack(const int* __restrict__ x, const float* __restrict__ ctxv,
                             const float* __restrict__ emb, const float* __restrict__ h0,
                             uint4* __restrict__ apk_rnn, uint4* __restrict__ apk_h0) {
    __shared__ float buf[1024];
    __shared__ float hbuf[512];
    const int b = blockIdx.x, t = threadIdx.x;
    const int row = x[b];
    if (t < 128) {
        ((float4*)buf)[t]  = ((const float4*)(emb + (size_t)row * EMBED))[t];
        ((float4*)hbuf)[t] = ((const float4*)(h0 + (size_t)b * HID))[t];
    } else {
        ((float4*)buf)[t] = ((const float4*)(ctxv + (size_t)b * HID))[t - 128];
    }
    __syncthreads();
    const int mt = b >> 4, lb = b & 15;
    if (t < 128) {                       // rnn frag t (K=1024)
        int kc = t >> 4, ksl = (t >> 2) & 3, kg = t & 3;
        apk_rnn[((kc * 8 + mt) * 4 + ksl) * 64 + kg * 16 + lb] = pk8(&buf[t * 8]);
    } else if (t < 192) {                // h0 frag (K=512)
        int i = t - 128;
        int kc = i >> 4, ksl = (i >> 2) & 3, kg = i & 3;
        apk_h0[((kc * 8 + mt) * 4 + ksl) * 64 + kg * 16 + lb] = pk8(&hbuf[i * 8]);
    }
}

// ---------------------------------------------------------------------------
// K2: 4-wave k-split MFMA GEMM. Block = 16 n-cols, all 128 m; wave w owns
// k-slices [w*K/128, (w+1)*K/128). Partial acc -> LDS -> reduce + epilogue.
// ---------------------------------------------------------------------------
template <int N, int K, int ACT, int HASB, int PACK>
__global__ __launch_bounds__(256, 2) void k_gemm_ks(
        const uint4* __restrict__ apk, const float* __restrict__ W,
        const float* __restrict__ bias, float* __restrict__ C,
        uint4* __restrict__ apk_out) {
    __shared__ float red[4][128][16];          // 32KB
    const int tid = threadIdx.x, lane = tid & 63, wv = tid >> 6;
    const int n0 = blockIdx.x * 16;
    const int ncol = n0 + (lane & 15);
    const int nc = ncol < N ? ncol : N - 1;
    const int kg = lane >> 4;
    constexpr int SPW = K / 128;               // slices per wave (4 or 8)
    f32x4 acc[8];
#pragma unroll
    for (int mt = 0; mt < 8; ++mt) acc[mt] = (f32x4)0.f;
    const float4* W4 = (const float4*)W;
    const size_t wb = (size_t)nc * (K / 4) + kg * 2;
#pragma unroll
    for (int s = 0; s < SPW; ++s) {
        const int ks = wv * SPW + s;
        float4 w0 = W4[wb + ks * 8];
        float4 w1 = W4[wb + ks * 8 + 1];
        short8 bf = __builtin_bit_cast(short8, pk8v(w0, w1));
        const uint4* ap = apk + (((ks >> 2) * 8) * 4 + (ks & 3)) * 64 + lane;
#pragma unroll
        for (int mt = 0; mt < 8; ++mt) {
            short8 af = __builtin_bit_cast(short8, ap[mt * 256]);
            acc[mt] = __builtin_amdgcn_mfma_f32_16x16x32_bf16(af, bf, acc[mt], 0, 0, 0);
        }
    }
#pragma unroll
    for (int mt = 0; mt < 8; ++mt)
#pragma unroll
        for (int j = 0; j < 4; ++j)
            red[wv][mt * 16 + kg * 4 + j][lane & 15] = acc[mt][j];
    __syncthreads();
#pragma unroll
    for (int i = 0; i < 8; ++i) {
        int o = tid + i * 256;
        int r = o >> 4, c = o & 15;
        float v = red[0][r][c] + red[1][r][c] + red[2][r][c] + red[3][r][c];
        if (HASB) v += bias[n0 + c];
        if (ACT) v = tanhf(v);
        C[(size_t)r * N + n0 + c] = v;
        if (PACK) red[0][r][c] = v;            // own (r,c) slot only
    }
    if constexpr (PACK) {
        __syncthreads();
        int r = tid >> 1, hf = tid & 1;        // 256 frags
        float tmp[8];
#pragma unroll
        for (int z = 0; z < 8; ++z) tmp[z] = red[0][r][hf * 8 + z];
        int k0 = n0 + hf * 8;
        int kc = k0 >> 7, ksl = (k0 >> 5) & 3, kg2 = (k0 >> 3) & 3;
        apk_out[((kc * 8 + (r >> 4)) * 4 + ksl) * 64 + kg2 * 16 + (r & 15)] = pk8(tmp);
    }
}

// ---------------------------------------------------------------------------
// K3: GRU gate combine (r,z,n) + pack h fragments (K=512)
// ---------------------------------------------------------------------------
__global__ void k_gru(const float* __restrict__ gi, const float* __restrict__ gh,
                      const float* __restrict__ h0, float* __restrict__ h,
                      uint4* __restrict__ apk_h) {
    __shared__ float hsh[256];
    const int t = threadIdx.x;
    const int idx = blockIdx.x * 256 + t;
    const int b = blockIdx.x >> 1, half = blockIdx.x & 1;
    const int j = half * 256 + t;
    const float* gib = gi + (size_t)b * 1536;
    const float* ghb = gh + (size_t)b * 1536;
    float ir = gib[j], iz = gib[512 + j], inn = gib[1024 + j];
    float hr = ghb[j], hz = ghb[512 + j], hn = ghb[1024 + j];
    float r = 1.f / (1.f + expf(-(ir + hr)));
    float z = 1.f / (1.f + expf(-(iz + hz)));
    float nn = tanhf(inn + r * hn);
    float hv = (1.f - z) * nn + z * h0[idx];
    h[idx] = hv;
    hsh[t] = hv;
    __syncthreads();
    if (t < 32) {
        int k0 = half * 256 + t * 8;
        int kc = k0 >> 7, ksl = (k0 >> 5) & 3, kg = (k0 >> 3) & 3;
        apk_h[((kc * 8 + (b >> 4)) * 4 + ksl) * 64 + kg * 16 + (b & 15)] = pk8(&hsh[t * 8]);
    }
}

// ---------------------------------------------------------------------------
// K4: attention (512 threads)
// ---------------------------------------------------------------------------
__global__ __launch_bounds__(512) void k_attn(const float* __restrict__ enc,
        const float* __restrict__ q, const int* __restrict__ lens,
        const float* __restrict__ h, float* __restrict__ a_out,
        uint4* __restrict__ apk_cat) {
    __shared__ float qs[512];
    __shared__ float red[128];
    __shared__ float aw[128];
    __shared__ float catsh[1024];
    const int b = blockIdx.x, t = threadIdx.x;
    qs[t] = q[(size_t)b * 512 + t];
    __syncthreads();
    const int srow = t >> 2, part = t & 3;
    const float* ep = enc + ((size_t)b * SRC + srow) * 512 + part * 128;
    float s = 0.f;
#pragma unroll
    for (int k4 = 0; k4 < 32; ++k4) {
        float4 e = ((const float4*)ep)[k4];
        float4 qq = *(const float4*)&qs[part * 128 + k4 * 4];
        s = fmaf(e.x, qq.x, fmaf(e.y, qq.y, fmaf(e.z, qq.z, fmaf(e.w, qq.w, s))));
    }
    s += __shfl_xor(s, 1);
    s += __shfl_xor(s, 2);
    if (part == 0) {
        int len = lens[b];
        float val = (srow < len) ? s : 0.f;
        if (val == 0.f) val = -1e10f;   // replicate ref's where(masked==0,-1e10)
        red[srow] = val;
        aw[srow] = val;
    }
    __syncthreads();
    for (int off = 64; off > 0; off >>= 1) {          // max tree
        if (t < off) red[t] = fmaxf(red[t], red[t + off]);
        __syncthreads();
    }
    float mx = red[0];
    __syncthreads();
    if (t < 128) { float e = expf(aw[t] - mx); aw[t] = e; red[t] = e; }
    __syncthreads();
    for (int off = 64; off > 0; off >>= 1) {          // sum tree
        if (t < off) red[t] += red[t + off];
        __syncthreads();
    }
    float denom = red[0];
    if (t < 128) {
        float av = aw[t] / denom;
        aw[t] = av;
        a_out[(size_t)t * B + b] = av;                // layout [S][B]
    }
    __syncthreads();
    float a0 = 0.f;
    const float* e2 = enc + (size_t)b * (SRC * 512) + t;
#pragma unroll 4
    for (int s2 = 0; s2 < SRC; ++s2) a0 = fmaf(aw[s2], e2[(size_t)s2 * 512], a0);
    catsh[t] = a0;
    catsh[512 + t] = h[(size_t)b * 512 + t];
    __syncthreads();
    if (t < 128) {                                    // pack cat frag (K=1024)
        int kc = t >> 4, ksl = (t >> 2) & 3, kg = t & 3;
        apk_cat[((kc * 8 + (b >> 4)) * 4 + ksl) * 64 + kg * 16 + (b & 15)] =
            pk8(&catsh[t * 8]);
    }
}

// ---------------------------------------------------------------------------
// K5a: fc1 persistent GEMM, packed-W path: A (128KB) in LDS once; W read as
// pre-packed bf16 fragments — every wave load is 64 consecutive uint4 (1KB
// contiguous), 16 issued per tile as one burst (natural counted vmcnt).
// ---------------------------------------------------------------------------
__global__ __launch_bounds__(512, 1) void k_fc1w(
        const uint4* __restrict__ apk, const uint4* __restrict__ wpk,
        const float* __restrict__ bias, float* __restrict__ C,
        float2* __restrict__ pout) {
    __shared__ uint4 As[8192];                 // 128KB: ALL of packed A
    __shared__ float2 pms[2][8][128];          // dbuf LSE partials
    const int tid = threadIdx.x, lane = tid & 63, wv = tid >> 6;
    const int kg = lane >> 4;
#pragma unroll
    for (int it = 0; it < 16; ++it)            // stage A once
        gll16(apk + it * 512 + tid, As + it * 512 + tid);
    __syncthreads();
    int pb = 0;
    for (int nt = blockIdx.x; nt < NT393; nt += 256) {
        const int cb = nt * 8 + wv;            // wave's 16-col group
        const int ncol = cb * 16 + (lane & 15);
        const bool valid = ncol < VOCAB;
        const uint4* wp = wpk + (size_t)(cb < WPKG ? cb : WPKG - 1) * 1024 + lane;
        uint4 wf[16];
#pragma unroll
        for (int ks = 0; ks < 16; ++ks) wf[ks] = wp[ks * 64];
        f32x4 acc[8];
#pragma unroll
        for (int mt = 0; mt < 8; ++mt) acc[mt] = (f32x4)0.f;
#pragma unroll
        for (int ks = 0; ks < 16; ++ks) {
            short8 bf = __builtin_bit_cast(short8, wf[ks]);
            const int base = ((ks >> 2) * 32 + (ks & 3)) * 64 + lane;
#pragma unroll
            for (int mt = 0; mt < 8; ++mt) {
                short8 af = __builtin_bit_cast(short8, As[base + mt * 256]);
                acc[mt] = __builtin_amdgcn_mfma_f32_16x16x32_bf16(af, bf, acc[mt], 0, 0, 0);
            }
        }
        float bb = bias[valid ? ncol : VOCAB - 1];
#pragma unroll
        for (int mt = 0; mt < 8; ++mt) {
#pragma unroll
            for (int j = 0; j < 4; ++j) {
                float v = acc[mt][j] + bb;
                int row = mt * 16 + kg * 4 + j;
                if (valid) C[(size_t)row * VOCAB + ncol] = v;
                float val = valid ? v : -1e30f;
                float m16 = val;
                m16 = fmaxf(m16, __shfl_xor(m16, 1));
                m16 = fmaxf(m16, __shfl_xor(m16, 2));
                m16 = fmaxf(m16, __shfl_xor(m16, 4));
                m16 = fmaxf(m16, __shfl_xor(m16, 8));
                float e = valid ? __expf(val - m16) : 0.f;
                e += __shfl_xor(e, 1);
                e += __shfl_xor(e, 2);
                e += __shfl_xor(e, 4);
                e += __shfl_xor(e, 8);
                if ((lane & 15) == 0) pms[pb][wv][row] = make_float2(m16, e);
            }
        }
        __syncthreads();
        if (tid < 128) {
            float2 p = pms[pb][0][tid];
            float m = p.x, s = p.y;
#pragma unroll
            for (int w = 1; w < 8; ++w) {
                float2 p2 = pms[pb][w][tid];
                float mm = fmaxf(m, p2.x);
                s = s * __expf(m - mm) + p2.y * __expf(p2.x - mm);
                m = mm;
            }
            pout[(size_t)tid * NT393 + nt] = make_float2(m, s);
        }
        pb ^= 1;
    }
}

// ---------------------------------------------------------------------------
// K5b: fc1 fallback (round-8 path, f32 W streamed with reg double-buffer)
// ---------------------------------------------------------------------------
#define FC1_LOADC(dst, wbase, c)                                        \
    _Pragma("unroll")                                                   \
    for (int q = 0; q < 4; ++q) {                                       \
        dst[2 * q]     = W4[(wbase) + (size_t)((4 * (c) + q) * 8)];     \
        dst[2 * q + 1] = W4[(wbase) + (size_t)((4 * (c) + q) * 8 + 1)]; \
    }
#define FC1_CONS(src, c)                                                \
    _Pragma("unroll")                                                   \
    for (int q = 0; q < 4; ++q) {                                       \
        short8 bf = __builtin_bit_cast(short8, pk8v(src[2 * q], src[2 * q + 1])); \
        const int base = ((c) * 32 + q) * 64 + lane;                    \
        _Pragma("unroll")                                               \
        for (int mt = 0; mt < 8; ++mt) {                                \
            short8 af = __builtin_bit_cast(short8, As[base + mt * 256]);\
            acc[mt] = __builtin_amdgcn_mfma_f32_16x16x32_bf16(af, bf, acc[mt], 0, 0, 0); \
        }                                                               \
    }

__global__ __launch_bounds__(512, 2) void k_fc1p(
        const uint4* __restrict__ apk, const float* __restrict__ W,
        const float* __restrict__ bias, float* __restrict__ C,
        float2* __restrict__ pout) {
    __shared__ uint4 As[8192];
    __shared__ float2 pms[2][8][128];
    const int tid = threadIdx.x, lane = tid & 63, wv = tid >> 6;
    const int kg = lane >> 4;
#pragma unroll
    for (int it = 0; it < 16; ++it)
        gll16(apk + it * 512 + tid, As + it * 512 + tid);
    __syncthreads();
    const float4* W4 = (const float4*)W;
    float4 Ab[8], Bb[8];
    int nt0 = blockIdx.x;
    size_t wb;
    {
        int ncol0 = nt0 * 128 + wv * 16 + (lane & 15);
        wb = (size_t)(ncol0 < VOCAB ? ncol0 : VOCAB - 1) * 128 + kg * 2;
        FC1_LOADC(Ab, wb, 0);
    }
    int pb = 0;
    for (int nt = nt0; nt < NT393; nt += 256) {
        const int ncol = nt * 128 + wv * 16 + (lane & 15);
        const bool valid = ncol < VOCAB;
        const int nc = valid ? ncol : VOCAB - 1;
        const int ntn = (nt + 256 < NT393) ? nt + 256 : NT393 - 1;
        const int ncoln = ntn * 128 + wv * 16 + (lane & 15);
        const size_t wbn = (size_t)(ncoln < VOCAB ? ncoln : VOCAB - 1) * 128 + kg * 2;
        f32x4 acc[8];
#pragma unroll
        for (int mt = 0; mt < 8; ++mt) acc[mt] = (f32x4)0.f;
        FC1_LOADC(Bb, wb, 1);
        FC1_CONS(Ab, 0);
        FC1_LOADC(Ab, wb, 2);
        FC1_CONS(Bb, 1);
        FC1_LOADC(Bb, wb, 3);
        FC1_CONS(Ab, 2);
        FC1_LOADC(Ab, wbn, 0);
        FC1_CONS(Bb, 3);
        float bb = bias[nc];
#pragma unroll
        for (int mt = 0; mt < 8; ++mt) {
#pragma unroll
            for (int j = 0; j < 4; ++j) {
                float v = acc[mt][j] + bb;
                int row = mt * 16 + kg * 4 + j;
                if (valid) C[(size_t)row * VOCAB + ncol] = v;
                if (pout) {
                    float val = valid ? v : -1e30f;
                    float m16 = val;
                    m16 = fmaxf(m16, __shfl_xor(m16, 1));
                    m16 = fmaxf(m16, __shfl_xor(m16, 2));
                    m16 = fmaxf(m16, __shfl_xor(m16, 4));
                    m16 = fmaxf(m16, __shfl_xor(m16, 8));
                    float e = valid ? __expf(val - m16) : 0.f;
                    e += __shfl_xor(e, 1);
                    e += __shfl_xor(e, 2);
                    e += __shfl_xor(e, 4);
                    e += __shfl_xor(e, 8);
                    if ((lane & 15) == 0) pms[pb][wv][row] = make_float2(m16, e);
                }
            }
        }
        if (pout) {
            __syncthreads();
            if (tid < 128) {
                float2 p = pms[pb][0][tid];
                float m = p.x, s = p.y;
#pragma unroll
                for (int w = 1; w < 8; ++w) {
                    float2 p2 = pms[pb][w][tid];
                    float mm = fmaxf(m, p2.x);
                    s = s * __expf(m - mm) + p2.y * __expf(p2.x - mm);
                    m = mm;
                }
                pout[(size_t)tid * NT393 + nt] = make_float2(m, s);
            }
            pb ^= 1;
        }
        wb = wbn;
    }
}

// ---------------------------------------------------------------------------
// K6a: merge per-tile LSE partials -> L[row]
// ---------------------------------------------------------------------------
__global__ __launch_bounds__(256) void k_lse_final(const float2* __restrict__ pout,
                                                   float* __restrict__ L, int nblk) {
    const int row = blockIdx.x, t = threadIdx.x;
    float m = -1e30f, s = 0.f;
    for (int i = t; i < nblk; i += 256) {
        float2 p = pout[(size_t)row * nblk + i];
        float mm = fmaxf(m, p.x);
        s = s * __expf(m - mm) + p.y * __expf(p.x - mm);
        m = mm;
    }
    __shared__ float sm[256], ss[256];
    sm[t] = m; ss[t] = s; __syncthreads();
    for (int off = 128; off > 0; off >>= 1) {
        if (t < off) {
            float m2 = sm[t + off], s2 = ss[t + off];
            float mm = fmaxf(sm[t], m2);
            ss[t] = ss[t] * __expf(sm[t] - mm) + s2 * __expf(m2 - mm);
            sm[t] = mm;
        }
        __syncthreads();
    }
    if (t == 0) L[row] = sm[0] + logf(ss[0]);
}

// ---------------------------------------------------------------------------
// K6b: log_probs = logits - L[b]  (in place), full-machine grid
// ---------------------------------------------------------------------------
__global__ __launch_bounds__(512) void k_lsub(float* __restrict__ logits,
                                              const float* __restrict__ L) {
    const int b = blockIdx.y;
    const float l = L[b];
    float* row = logits + (size_t)b * VOCAB;
    int c0 = (blockIdx.x * 512 + threadIdx.x) * 4;
    if (c0 + 4 <= VOCAB) {
        float4 x = *(float4*)(row + c0);
        x.x -= l; x.y -= l; x.z -= l; x.w -= l;
        *(float4*)(row + c0) = x;
    } else {
        for (int c = c0; c < VOCAB; ++c) row[c] -= l;
    }
}

// ---------------------------------------------------------------------------
// K6-fallback: fused log-softmax (online LSE + in-place subtract)
// ---------------------------------------------------------------------------
__global__ __launch_bounds__(1024) void k_lse_sub(float* __restrict__ logits) {
    const int b = blockIdx.x, t = threadIdx.x;
    float* row = logits + (size_t)b * VOCAB;
    const int N4 = VOCAB >> 2;
    float m = -1e30f, s = 0.f;
    for (int i = t; i < N4; i += 1024) {
        float4 x = ((const float4*)row)[i];
        float xs[4] = {x.x, x.y, x.z, x.w};
#pragma unroll
        for (int j = 0; j < 4; ++j) {
            float v = xs[j];
            if (v > m) { s = s * __expf(m - v) + 1.f; m = v; }
            else        s += __expf(v - m);
        }
    }
    if (t == 0) {
        float v = row[VOCAB - 1];
        if (v > m) { s = s * __expf(m - v) + 1.f; m = v; }
        else        s += __expf(v - m);
    }
    __shared__ float sm[1024], ss[1024];
    sm[t] = m; ss[t] = s;
    __syncthreads();
    for (int off = 512; off > 0; off >>= 1) {
        if (t < off) {
            float m2 = sm[t + off], s2 = ss[t + off];
            float mm = fmaxf(sm[t], m2);
            ss[t] = ss[t] * __expf(sm[t] - mm) + s2 * __expf(m2 - mm);
            sm[t] = mm;
        }
        __syncthreads();
    }
    __shared__ float Lsh;
    if (t == 0) Lsh = sm[0] + logf(ss[0]);
    __syncthreads();
    float L = Lsh;
    for (int i = t; i < N4; i += 1024) {
        float4 x = ((const float4*)row)[i];
        x.x -= L; x.y -= L; x.z -= L; x.w -= L;
        ((float4*)row)[i] = x;
    }
    if (t == 0) row[VOCAB - 1] -= L;
}

// ---------------------------------------------------------------------------
extern "C" void kernel_launch(void* const* d_in, const int* in_sizes, int n_in,
                              void* d_out, int out_size, void* d_ws, size_t ws_size,
                              hipStream_t stream) {
    const int*   x    = (const int*)d_in[0];
    const float* h0   = (const float*)d_in[1];   // decoder_hidden [1,B,H]
    const int*   lens = (const int*)d_in[2];
    const float* enc  = (const float*)d_in[3];   // [B,SRC,H]
    const float* ctxv = (const float*)d_in[4];   // [B,H]
    const float* emb  = (const float*)d_in[5];   // [V,E]
    const float* wih  = (const float*)d_in[6];   // [1536,1024]
    const float* whh  = (const float*)d_in[7];   // [1536,512]
    const float* bih  = (const float*)d_in[8];
    const float* bhh  = (const float*)d_in[9];
    const float* Wa   = (const float*)d_in[10];  // [512,512]
    const float* Wc   = (const float*)d_in[11];  // [512,1024]
    const float* fc1w = (const float*)d_in[12];  // [V,512]
    const float* fc1b = (const float*)d_in[13];

    float* out     = (float*)d_out;
    float* outLogp = out;                                  // [B][VOCAB]
    float* outHid  = out + (size_t)B * VOCAB;              // [B][HID]
    float* outA    = outHid + (size_t)B * HID;             // [SRC][B]
    float* outCtx  = outA + (size_t)SRC * B;               // [B][HID]

    // scratch inside the not-yet-written log_probs region (6.43M floats)
    float* gi = outLogp;                                   // [B][1536]
    float* gh = gi + B * 1536;                             // [B][1536]
    float* q  = gh + B * 1536;                             // [B][512]
    uint4* apk_rnn = (uint4*)(q + B * HID);                // 16384 u4 (K=1024)
    uint4* apk_h0  = apk_rnn + 16384;                      // 8192  u4 (K=512)
    uint4* apk_h   = apk_h0 + 8192;                        // 8192  u4 (K=512)
    uint4* apk_cat = apk_h + 8192;                         // 16384 u4 (K=1024)

    uint4*  apk_ctx = (uint4*)d_ws;                        // 128KB (survives fc1)
    size_t  off_pout = 131072;
    size_t  off_L    = off_pout + (size_t)B * NT393 * sizeof(float2);   // 533504
    size_t  off_wpk  = 534016;                              // 512-aligned
    size_t  wpk_bytes = (size_t)WPKG * 1024 * 16;           // 51.5MB
    bool bigws  = ws_size >= off_L + 512;
    bool bigws2 = ws_size >= off_wpk + wpk_bytes;
    float2* pout = bigws ? (float2*)((char*)d_ws + off_pout) : nullptr;
    float*  Lb   = bigws ? (float*)((char*)d_ws + off_L) : nullptr;
    uint4*  wpk  = bigws2 ? (uint4*)((char*)d_ws + off_wpk) : nullptr;

    if (bigws2)   // dedicated W f32->bf16 fragment conversion (no deps)
        k_wconv<<<dim3(786), dim3(256), 0, stream>>>(fc1w, wpk);

    k_embed_pack<<<dim3(B), dim3(256), 0, stream>>>(x, ctxv, emb, h0, apk_rnn, apk_h0);
    k_gemm_ks<1536, 1024, 0, 1, 0><<<dim3(96), dim3(256), 0, stream>>>(
        apk_rnn, wih, bih, gi, nullptr);
    k_gemm_ks<1536, 512, 0, 1, 0><<<dim3(96), dim3(256), 0, stream>>>(
        apk_h0, whh, bhh, gh, nullptr);
    k_gru<<<dim3(256), dim3(256), 0, stream>>>(gi, gh, h0, outHid, apk_h);
    k_gemm_ks<512, 512, 0, 0, 0><<<dim3(32), dim3(256), 0, stream>>>(
        apk_h, Wa, nullptr, q, nullptr);
    k_attn<<<dim3(B), dim3(512), 0, stream>>>(enc, q, lens, outHid, outA, apk_cat);
    k_gemm_ks<512, 1024, 1, 0, 1><<<dim3(32), dim3(256), 0, stream>>>(
        apk_cat, Wc, nullptr, outCtx, apk_ctx);
    if (bigws2) {
        k_fc1w<<<dim3(256), dim3(512), 0, stream>>>(apk_ctx, wpk, fc1b, outLogp, pout);
        k_lse_final<<<dim3(B), dim3(256), 0, stream>>>(pout, Lb, NT393);
        k_lsub<<<dim3(25, B), dim3(512), 0, stream>>>(outLogp, Lb);
    } else if (bigws) {
        k_fc1p<<<dim3(256), dim3(512), 0, stream>>>(apk_ctx, fc1w, fc1b, outLogp, pout);
        k_lse_final<<<dim3(B), dim3(256), 0, stream>>>(pout, Lb, NT393);
        k_lsub<<<dim3(25, B), dim3(512), 0, stream>>>(outLogp, Lb);
    } else {
        k_fc1p<<<dim3(256), dim3(512), 0, stream>>>(apk_ctx, fc1w, fc1b, outLogp, nullptr);
        k_lse_sub<<<dim3(B), dim3(1024), 0, stream>>>(outLogp);
    }
}

// Round 12
// 136.192 us; speedup vs baseline: 1.0582x; 1.0582x over previous
//
#include <hip/hip_runtime.h>

#define VOCAB 50257
#define EMBED 512
#define HID   512
#define B     128
#define SRC   128
#define FBLK  1571       // fc1 blocks: ceil(50257/32) cols, 32 per 1-wave block

typedef __attribute__((ext_vector_type(8))) short short8;
typedef __attribute__((ext_vector_type(4))) float f32x4;

// f32 -> bf16 (round-to-nearest-even), result in low 16 bits
__device__ __forceinline__ unsigned f2bf(float x) {
    unsigned u = __builtin_bit_cast(unsigned, x);
    return (u + 0x7fffu + ((u >> 16) & 1u)) >> 16;
}
__device__ __forceinline__ unsigned pk2(float lo, float hi) {
    return f2bf(lo) | (f2bf(hi) << 16);
}
__device__ __forceinline__ uint4 pk8(const float* p) {
    uint4 r;
    r.x = pk2(p[0], p[1]); r.y = pk2(p[2], p[3]);
    r.z = pk2(p[4], p[5]); r.w = pk2(p[6], p[7]);
    return r;
}
__device__ __forceinline__ uint4 pk8v(float4 a, float4 b) {
    uint4 r;
    r.x = pk2(a.x, a.y); r.y = pk2(a.z, a.w);
    r.z = pk2(b.x, b.y); r.w = pk2(b.z, b.w);
    return r;
}

// Fragment-packed A layout (bf16, mfma_f32_16x16x32_bf16 A-operand order):
// uint4 index = ((kc*8 + mt)*4 + ksl)*64 + kg*16 + (row&15)
//   row = mt*16 + (row&15), k = kc*128 + ksl*32 + kg*8 + j (j=0..7)

// ---------------------------------------------------------------------------
// K1: pack rnn_in = [emb(x[b]) | ctxv[b]]  (K=1024) and h0[b]  (K=512)
// ---------------------------------------------------------------------------
__global__ void k_embed_pack(const int* __restrict__ x, const float* __restrict__ ctxv,
                             const float* __restrict__ emb, const float* __restrict__ h0,
                             uint4* __restrict__ apk_rnn, uint4* __restrict__ apk_h0) {
    __shared__ float buf[1024];
    __shared__ float hbuf[512];
    const int b = blockIdx.x, t = threadIdx.x;
    const int row = x[b];
    if (t < 128) {
        ((float4*)buf)[t]  = ((const float4*)(emb + (size_t)row * EMBED))[t];
        ((float4*)hbuf)[t] = ((const float4*)(h0 + (size_t)b * HID))[t];
    } else {
        ((float4*)buf)[t] = ((const float4*)(ctxv + (size_t)b * HID))[t - 128];
    }
    __syncthreads();
    const int mt = b >> 4, lb = b & 15;
    if (t < 128) {                       // rnn frag t (K=1024)
        int kc = t >> 4, ksl = (t >> 2) & 3, kg = t & 3;
        apk_rnn[((kc * 8 + mt) * 4 + ksl) * 64 + kg * 16 + lb] = pk8(&buf[t * 8]);
    } else if (t < 192) {                // h0 frag (K=512)
        int i = t - 128;
        int kc = i >> 4, ksl = (i >> 2) & 3, kg = i & 3;
        apk_h0[((kc * 8 + mt) * 4 + ksl) * 64 + kg * 16 + lb] = pk8(&hbuf[i * 8]);
    }
}

// ---------------------------------------------------------------------------
// K2a: MERGED gi/gh GEMM (both N=1536, bias, no act): blocks [0,96) compute
// gi = rnn_in @ wih^T (K=1024); blocks [96,192) compute gh = h0 @ whh^T
// (K=512). 4-wave k-split, runtime K.
// ---------------------------------------------------------------------------
__global__ __launch_bounds__(256, 2) void k_gemm2(
        const uint4* __restrict__ apkA, const float* __restrict__ WA,
        const float* __restrict__ bA, float* __restrict__ CA, int KA,
        const uint4* __restrict__ apkB, const float* __restrict__ WB,
        const float* __restrict__ bB, float* __restrict__ CB, int KB,
        int nblkA) {
    const bool isB = (int)blockIdx.x >= nblkA;
    const uint4* apk = isB ? apkB : apkA;
    const float* W   = isB ? WB : WA;
    const float* bias= isB ? bB : bA;
    float* C         = isB ? CB : CA;
    const int K      = isB ? KB : KA;
    const int bid    = isB ? (int)blockIdx.x - nblkA : (int)blockIdx.x;
    const int N = 1536;
    __shared__ float red[4][128][16];          // 32KB
    const int tid = threadIdx.x, lane = tid & 63, wv = tid >> 6;
    const int n0 = bid * 16;
    const int ncol = n0 + (lane & 15);         // < 1536 always
    const int kg = lane >> 4;
    const int spw = K >> 7;                    // slices per wave (8 or 4)
    f32x4 acc[8];
#pragma unroll
    for (int mt = 0; mt < 8; ++mt) acc[mt] = (f32x4)0.f;
    const float4* W4 = (const float4*)W;
    const size_t wb = (size_t)ncol * (K >> 2) + kg * 2;
    for (int s = 0; s < spw; ++s) {
        const int ks = wv * spw + s;
        float4 w0 = W4[wb + ks * 8];
        float4 w1 = W4[wb + ks * 8 + 1];
        short8 bf = __builtin_bit_cast(short8, pk8v(w0, w1));
        const uint4* ap = apk + ((size_t)(ks >> 2) * 32 + (ks & 3)) * 64 + lane;
#pragma unroll
        for (int mt = 0; mt < 8; ++mt) {
            short8 af = __builtin_bit_cast(short8, ap[mt * 256]);
            acc[mt] = __builtin_amdgcn_mfma_f32_16x16x32_bf16(af, bf, acc[mt], 0, 0, 0);
        }
    }
#pragma unroll
    for (int mt = 0; mt < 8; ++mt)
#pragma unroll
        for (int j = 0; j < 4; ++j)
            red[wv][mt * 16 + kg * 4 + j][lane & 15] = acc[mt][j];
    __syncthreads();
#pragma unroll
    for (int i = 0; i < 8; ++i) {
        int o = tid + i * 256;
        int r = o >> 4, c = o & 15;
        float v = red[0][r][c] + red[1][r][c] + red[2][r][c] + red[3][r][c];
        v += bias[n0 + c];
        C[(size_t)r * N + n0 + c] = v;
    }
}

// ---------------------------------------------------------------------------
// K2b: 4-wave k-split MFMA GEMM (Wa / Wc), compile-time config.
// ---------------------------------------------------------------------------
template <int N, int K, int ACT, int HASB, int PACK>
__global__ __launch_bounds__(256, 2) void k_gemm_ks(
        const uint4* __restrict__ apk, const float* __restrict__ W,
        const float* __restrict__ bias, float* __restrict__ C,
        uint4* __restrict__ apk_out) {
    __shared__ float red[4][128][16];          // 32KB
    const int tid = threadIdx.x, lane = tid & 63, wv = tid >> 6;
    const int n0 = blockIdx.x * 16;
    const int ncol = n0 + (lane & 15);
    const int nc = ncol < N ? ncol : N - 1;
    const int kg = lane >> 4;
    constexpr int SPW = K / 128;               // slices per wave (4 or 8)
    f32x4 acc[8];
#pragma unroll
    for (int mt = 0; mt < 8; ++mt) acc[mt] = (f32x4)0.f;
    const float4* W4 = (const float4*)W;
    const size_t wb = (size_t)nc * (K / 4) + kg * 2;
#pragma unroll
    for (int s = 0; s < SPW; ++s) {
        const int ks = wv * SPW + s;
        float4 w0 = W4[wb + ks * 8];
        float4 w1 = W4[wb + ks * 8 + 1];
        short8 bf = __builtin_bit_cast(short8, pk8v(w0, w1));
        const uint4* ap = apk + (((ks >> 2) * 8) * 4 + (ks & 3)) * 64 + lane;
#pragma unroll
        for (int mt = 0; mt < 8; ++mt) {
            short8 af = __builtin_bit_cast(short8, ap[mt * 256]);
            acc[mt] = __builtin_amdgcn_mfma_f32_16x16x32_bf16(af, bf, acc[mt], 0, 0, 0);
        }
    }
#pragma unroll
    for (int mt = 0; mt < 8; ++mt)
#pragma unroll
        for (int j = 0; j < 4; ++j)
            red[wv][mt * 16 + kg * 4 + j][lane & 15] = acc[mt][j];
    __syncthreads();
#pragma unroll
    for (int i = 0; i < 8; ++i) {
        int o = tid + i * 256;
        int r = o >> 4, c = o & 15;
        float v = red[0][r][c] + red[1][r][c] + red[2][r][c] + red[3][r][c];
        if (HASB) v += bias[n0 + c];
        if (ACT) v = tanhf(v);
        C[(size_t)r * N + n0 + c] = v;
        if (PACK) red[0][r][c] = v;            // own (r,c) slot only
    }
    if constexpr (PACK) {
        __syncthreads();
        int r = tid >> 1, hf = tid & 1;        // 256 frags
        float tmp[8];
#pragma unroll
        for (int z = 0; z < 8; ++z) tmp[z] = red[0][r][hf * 8 + z];
        int k0 = n0 + hf * 8;
        int kc = k0 >> 7, ksl = (k0 >> 5) & 3, kg2 = (k0 >> 3) & 3;
        apk_out[((kc * 8 + (r >> 4)) * 4 + ksl) * 64 + kg2 * 16 + (r & 15)] = pk8(tmp);
    }
}

// ---------------------------------------------------------------------------
// K3: GRU gate combine (r,z,n) + pack h fragments (K=512)
// ---------------------------------------------------------------------------
__global__ void k_gru(const float* __restrict__ gi, const float* __restrict__ gh,
                      const float* __restrict__ h0, float* __restrict__ h,
                      uint4* __restrict__ apk_h) {
    __shared__ float hsh[256];
    const int t = threadIdx.x;
    const int idx = blockIdx.x * 256 + t;
    const int b = blockIdx.x >> 1, half = blockIdx.x & 1;
    const int j = half * 256 + t;
    const float* gib = gi + (size_t)b * 1536;
    const float* ghb = gh + (size_t)b * 1536;
    float ir = gib[j], iz = gib[512 + j], inn = gib[1024 + j];
    float hr = ghb[j], hz = ghb[512 + j], hn = ghb[1024 + j];
    float r = 1.f / (1.f + expf(-(ir + hr)));
    float z = 1.f / (1.f + expf(-(iz + hz)));
    float nn = tanhf(inn + r * hn);
    float hv = (1.f - z) * nn + z * h0[idx];
    h[idx] = hv;
    hsh[t] = hv;
    __syncthreads();
    if (t < 32) {
        int k0 = half * 256 + t * 8;
        int kc = k0 >> 7, ksl = (k0 >> 5) & 3, kg = (k0 >> 3) & 3;
        apk_h[((kc * 8 + (b >> 4)) * 4 + ksl) * 64 + kg * 16 + (b & 15)] = pk8(&hsh[t * 8]);
    }
}

// ---------------------------------------------------------------------------
// K4: attention (512 threads)
// ---------------------------------------------------------------------------
__global__ __launch_bounds__(512) void k_attn(const float* __restrict__ enc,
        const float* __restrict__ q, const int* __restrict__ lens,
        const float* __restrict__ h, float* __restrict__ a_out,
        uint4* __restrict__ apk_cat) {
    __shared__ float qs[512];
    __shared__ float red[128];
    __shared__ float aw[128];
    __shared__ float catsh[1024];
    const int b = blockIdx.x, t = threadIdx.x;
    qs[t] = q[(size_t)b * 512 + t];
    __syncthreads();
    const int srow = t >> 2, part = t & 3;
    const float* ep = enc + ((size_t)b * SRC + srow) * 512 + part * 128;
    float s = 0.f;
#pragma unroll
    for (int k4 = 0; k4 < 32; ++k4) {
        float4 e = ((const float4*)ep)[k4];
        float4 qq = *(const float4*)&qs[part * 128 + k4 * 4];
        s = fmaf(e.x, qq.x, fmaf(e.y, qq.y, fmaf(e.z, qq.z, fmaf(e.w, qq.w, s))));
    }
    s += __shfl_xor(s, 1);
    s += __shfl_xor(s, 2);
    if (part == 0) {
        int len = lens[b];
        float val = (srow < len) ? s : 0.f;
        if (val == 0.f) val = -1e10f;   // replicate ref's where(masked==0,-1e10)
        red[srow] = val;
        aw[srow] = val;
    }
    __syncthreads();
    for (int off = 64; off > 0; off >>= 1) {          // max tree
        if (t < off) red[t] = fmaxf(red[t], red[t + off]);
        __syncthreads();
    }
    float mx = red[0];
    __syncthreads();
    if (t < 128) { float e = expf(aw[t] - mx); aw[t] = e; red[t] = e; }
    __syncthreads();
    for (int off = 64; off > 0; off >>= 1) {          // sum tree
        if (t < off) red[t] += red[t + off];
        __syncthreads();
    }
    float denom = red[0];
    if (t < 128) {
        float av = aw[t] / denom;
        aw[t] = av;
        a_out[(size_t)t * B + b] = av;                // layout [S][B]
    }
    __syncthreads();
    float a0 = 0.f;
    const float* e2 = enc + (size_t)b * (SRC * 512) + t;
#pragma unroll 4
    for (int s2 = 0; s2 < SRC; ++s2) a0 = fmaf(aw[s2], e2[(size_t)s2 * 512], a0);
    catsh[t] = a0;
    catsh[512 + t] = h[(size_t)b * 512 + t];
    __syncthreads();
    if (t < 128) {                                    // pack cat frag (K=1024)
        int kc = t >> 4, ksl = (t >> 2) & 3, kg = t & 3;
        apk_cat[((kc * 8 + (b >> 4)) * 4 + ksl) * 64 + kg * 16 + (b & 15)] =
            pk8(&catsh[t * 8]);
    }
}

// ---------------------------------------------------------------------------
// K5: fc1 DIRECT GEMM — one tile per wave, no LDS, no barriers, huge grid.
// 1571 blocks x 1 wave; wave owns 32 cols x all 128 m x full K=512.
// W loads: 16 rows x 128B full-line segments per instruction. A-fragments
// read straight from L2 (apk_ctx, 128KB hot). Fused per-block LSE partials.
// Even fully latency-serial waves finish concurrently (1571 waves ~ 1.5/SIMD).
// ---------------------------------------------------------------------------
__global__ __launch_bounds__(64) void k_fc1d(
        const uint4* __restrict__ apk, const float* __restrict__ W,
        const float* __restrict__ bias, float* __restrict__ C,
        float2* __restrict__ pout, int nblk) {
    const int lane = threadIdx.x;
    const int kg = lane >> 4;
    const int c0 = blockIdx.x * 32 + (lane & 15);
    const int c1 = c0 + 16;
    const int nc0 = c0 < VOCAB ? c0 : VOCAB - 1;
    const int nc1 = c1 < VOCAB ? c1 : VOCAB - 1;
    const float4* W4 = (const float4*)W;
    const size_t wb0 = (size_t)nc0 * 128 + kg * 2;
    const size_t wb1 = (size_t)nc1 * 128 + kg * 2;
    f32x4 acc0[8], acc1[8];
#pragma unroll
    for (int mt = 0; mt < 8; ++mt) { acc0[mt] = (f32x4)0.f; acc1[mt] = (f32x4)0.f; }
#pragma unroll
    for (int ks = 0; ks < 16; ++ks) {
        float4 wa0 = W4[wb0 + ks * 8];
        float4 wa1 = W4[wb0 + ks * 8 + 1];
        float4 wc0 = W4[wb1 + ks * 8];
        float4 wc1 = W4[wb1 + ks * 8 + 1];
        short8 bf0 = __builtin_bit_cast(short8, pk8v(wa0, wa1));
        short8 bf1 = __builtin_bit_cast(short8, pk8v(wc0, wc1));
        const uint4* ap = apk + ((size_t)(ks >> 2) * 32 + (ks & 3)) * 64 + lane;
#pragma unroll
        for (int mt = 0; mt < 8; ++mt) {
            short8 af = __builtin_bit_cast(short8, ap[mt * 256]);
            acc0[mt] = __builtin_amdgcn_mfma_f32_16x16x32_bf16(af, bf0, acc0[mt], 0, 0, 0);
            acc1[mt] = __builtin_amdgcn_mfma_f32_16x16x32_bf16(af, bf1, acc1[mt], 0, 0, 0);
        }
    }
    const float bb0 = bias[nc0], bb1 = bias[nc1];
#pragma unroll
    for (int mt = 0; mt < 8; ++mt) {
#pragma unroll
        for (int j = 0; j < 4; ++j) {
            const int row = mt * 16 + kg * 4 + j;
            float v0 = acc0[mt][j] + bb0;
            float v1 = acc1[mt][j] + bb1;
            if (c0 < VOCAB) C[(size_t)row * VOCAB + c0] = v0;
            if (c1 < VOCAB) C[(size_t)row * VOCAB + c1] = v1;
            if (pout) {
                float va = c0 < VOCAB ? v0 : -1e30f;
                float vb = c1 < VOCAB ? v1 : -1e30f;
                float m = fmaxf(va, vb);
                m = fmaxf(m, __shfl_xor(m, 1));
                m = fmaxf(m, __shfl_xor(m, 2));
                m = fmaxf(m, __shfl_xor(m, 4));
                m = fmaxf(m, __shfl_xor(m, 8));
                float e = (c0 < VOCAB ? __expf(va - m) : 0.f)
                        + (c1 < VOCAB ? __expf(vb - m) : 0.f);
                e += __shfl_xor(e, 1);
                e += __shfl_xor(e, 2);
                e += __shfl_xor(e, 4);
                e += __shfl_xor(e, 8);
                if ((lane & 15) == 0)
                    pout[(size_t)row * nblk + blockIdx.x] = make_float2(m, e);
            }
        }
    }
}

// ---------------------------------------------------------------------------
// K6a: merge per-block LSE partials -> L[row]
// ---------------------------------------------------------------------------
__global__ __launch_bounds__(256) void k_lse_final(const float2* __restrict__ pout,
                                                   float* __restrict__ L, int nblk) {
    const int row = blockIdx.x, t = threadIdx.x;
    float m = -1e30f, s = 0.f;
    for (int i = t; i < nblk; i += 256) {
        float2 p = pout[(size_t)row * nblk + i];
        float mm = fmaxf(m, p.x);
        s = s * __expf(m - mm) + p.y * __expf(p.x - mm);
        m = mm;
    }
    __shared__ float sm[256], ss[256];
    sm[t] = m; ss[t] = s; __syncthreads();
    for (int off = 128; off > 0; off >>= 1) {
        if (t < off) {
            float m2 = sm[t + off], s2 = ss[t + off];
            float mm = fmaxf(sm[t], m2);
            ss[t] = ss[t] * __expf(sm[t] - mm) + s2 * __expf(m2 - mm);
            sm[t] = mm;
        }
        __syncthreads();
    }
    if (t == 0) L[row] = sm[0] + logf(ss[0]);
}

// ---------------------------------------------------------------------------
// K6b: log_probs = logits - L[b]  (in place), full-machine grid
// ---------------------------------------------------------------------------
__global__ __launch_bounds__(512) void k_lsub(float* __restrict__ logits,
                                              const float* __restrict__ L) {
    const int b = blockIdx.y;
    const float l = L[b];
    float* row = logits + (size_t)b * VOCAB;
    int c0 = (blockIdx.x * 512 + threadIdx.x) * 4;
    if (c0 + 4 <= VOCAB) {
        float4 x = *(float4*)(row + c0);
        x.x -= l; x.y -= l; x.z -= l; x.w -= l;
        *(float4*)(row + c0) = x;
    } else {
        for (int c = c0; c < VOCAB; ++c) row[c] -= l;
    }
}

// ---------------------------------------------------------------------------
// K6-fallback: fused log-softmax (online LSE + in-place subtract)
// ---------------------------------------------------------------------------
__global__ __launch_bounds__(1024) void k_lse_sub(float* __restrict__ logits) {
    const int b = blockIdx.x, t = threadIdx.x;
    float* row = logits + (size_t)b * VOCAB;
    const int N4 = VOCAB >> 2;
    float m = -1e30f, s = 0.f;
    for (int i = t; i < N4; i += 1024) {
        float4 x = ((const float4*)row)[i];
        float xs[4] = {x.x, x.y, x.z, x.w};
#pragma unroll
        for (int j = 0; j < 4; ++j) {
            float v = xs[j];
            if (v > m) { s = s * __expf(m - v) + 1.f; m = v; }
            else        s += __expf(v - m);
        }
    }
    if (t == 0) {
        float v = row[VOCAB - 1];
        if (v > m) { s = s * __expf(m - v) + 1.f; m = v; }
        else        s += __expf(v - m);
    }
    __shared__ float sm[1024], ss[1024];
    sm[t] = m; ss[t] = s;
    __syncthreads();
    for (int off = 512; off > 0; off >>= 1) {
        if (t < off) {
            float m2 = sm[t + off], s2 = ss[t + off];
            float mm = fmaxf(sm[t], m2);
            ss[t] = ss[t] * __expf(sm[t] - mm) + s2 * __expf(m2 - mm);
            sm[t] = mm;
        }
        __syncthreads();
    }
    __shared__ float Lsh;
    if (t == 0) Lsh = sm[0] + logf(ss[0]);
    __syncthreads();
    float L = Lsh;
    for (int i = t; i < N4; i += 1024) {
        float4 x = ((const float4*)row)[i];
        x.x -= L; x.y -= L; x.z -= L; x.w -= L;
        ((float4*)row)[i] = x;
    }
    if (t == 0) row[VOCAB - 1] -= L;
}

// ---------------------------------------------------------------------------
extern "C" void kernel_launch(void* const* d_in, const int* in_sizes, int n_in,
                              void* d_out, int out_size, void* d_ws, size_t ws_size,
                              hipStream_t stream) {
    const int*   x    = (const int*)d_in[0];
    const float* h0   = (const float*)d_in[1];   // decoder_hidden [1,B,H]
    const int*   lens = (const int*)d_in[2];
    const float* enc  = (const float*)d_in[3];   // [B,SRC,H]
    const float* ctxv = (const float*)d_in[4];   // [B,H]
    const float* emb  = (const float*)d_in[5];   // [V,E]
    const float* wih  = (const float*)d_in[6];   // [1536,1024]
    const float* whh  = (const float*)d_in[7];   // [1536,512]
    const float* bih  = (const float*)d_in[8];
    const float* bhh  = (const float*)d_in[9];
    const float* Wa   = (const float*)d_in[10];  // [512,512]
    const float* Wc   = (const float*)d_in[11];  // [512,1024]
    const float* fc1w = (const float*)d_in[12];  // [V,512]
    const float* fc1b = (const float*)d_in[13];

    float* out     = (float*)d_out;
    float* outLogp = out;                                  // [B][VOCAB]
    float* outHid  = out + (size_t)B * VOCAB;              // [B][HID]
    float* outA    = outHid + (size_t)B * HID;             // [SRC][B]
    float* outCtx  = outA + (size_t)SRC * B;               // [B][HID]

    // scratch inside the not-yet-written log_probs region (6.43M floats)
    float* gi = outLogp;                                   // [B][1536]
    float* gh = gi + B * 1536;                             // [B][1536]
    float* q  = gh + B * 1536;                             // [B][512]
    uint4* apk_rnn = (uint4*)(q + B * HID);                // 16384 u4 (K=1024)
    uint4* apk_h0  = apk_rnn + 16384;                      // 8192  u4 (K=512)
    uint4* apk_h   = apk_h0 + 8192;                        // 8192  u4 (K=512)
    uint4* apk_cat = apk_h + 8192;                         // 16384 u4 (K=1024)

    uint4*  apk_ctx = (uint4*)d_ws;                        // 128KB (survives fc1)
    size_t  off_pout = 131072;
    size_t  off_L    = off_pout + (size_t)B * FBLK * sizeof(float2);
    bool bigws = ws_size >= off_L + 512;
    float2* pout = bigws ? (float2*)((char*)d_ws + off_pout) : nullptr;
    float*  Lb   = bigws ? (float*)((char*)d_ws + off_L) : nullptr;

    k_embed_pack<<<dim3(B), dim3(256), 0, stream>>>(x, ctxv, emb, h0, apk_rnn, apk_h0);
    k_gemm2<<<dim3(192), dim3(256), 0, stream>>>(
        apk_rnn, wih, bih, gi, 1024,
        apk_h0, whh, bhh, gh, 512, 96);
    k_gru<<<dim3(256), dim3(256), 0, stream>>>(gi, gh, h0, outHid, apk_h);
    k_gemm_ks<512, 512, 0, 0, 0><<<dim3(32), dim3(256), 0, stream>>>(
        apk_h, Wa, nullptr, q, nullptr);
    k_attn<<<dim3(B), dim3(512), 0, stream>>>(enc, q, lens, outHid, outA, apk_cat);
    k_gemm_ks<512, 1024, 1, 0, 1><<<dim3(32), dim3(256), 0, stream>>>(
        apk_cat, Wc, nullptr, outCtx, apk_ctx);
    k_fc1d<<<dim3(FBLK), dim3(64), 0, stream>>>(apk_ctx, fc1w, fc1b, outLogp,
                                                pout, FBLK);
    if (bigws) {
        k_lse_final<<<dim3(B), dim3(256), 0, stream>>>(pout, Lb, FBLK);
        k_lsub<<<dim3(25, B), dim3(512), 0, stream>>>(outLogp, Lb);
    } else {
        k_lse_sub<<<dim3(B), dim3(1024), 0, stream>>>(outLogp);
    }
}

// Round 13
// 117.815 us; speedup vs baseline: 1.2233x; 1.1560x over previous
//
#include <hip/hip_runtime.h>

#define VOCAB 50257
#define EMBED 512
#define HID   512
#define B     128
#define SRC   128
#define FBLK2 3142       // fc1 blocks: ceil(50257/16) cols, 16 per 1-wave block

typedef __attribute__((ext_vector_type(8))) short short8;
typedef __attribute__((ext_vector_type(4))) float f32x4;

// f32 -> bf16 (round-to-nearest-even), result in low 16 bits
__device__ __forceinline__ unsigned f2bf(float x) {
    unsigned u = __builtin_bit_cast(unsigned, x);
    return (u + 0x7fffu + ((u >> 16) & 1u)) >> 16;
}
__device__ __forceinline__ unsigned pk2(float lo, float hi) {
    return f2bf(lo) | (f2bf(hi) << 16);
}
__device__ __forceinline__ uint4 pk8(const float* p) {
    uint4 r;
    r.x = pk2(p[0], p[1]); r.y = pk2(p[2], p[3]);
    r.z = pk2(p[4], p[5]); r.w = pk2(p[6], p[7]);
    return r;
}
__device__ __forceinline__ uint4 pk8v(float4 a, float4 b) {
    uint4 r;
    r.x = pk2(a.x, a.y); r.y = pk2(a.z, a.w);
    r.z = pk2(b.x, b.y); r.w = pk2(b.z, b.w);
    return r;
}

// Fragment-packed A layout (bf16, mfma_f32_16x16x32_bf16 A-operand order):
// uint4 index = ((kc*8 + mt)*4 + ksl)*64 + kg*16 + (row&15)
//   row = mt*16 + (row&15), k = kc*128 + ksl*32 + kg*8 + j (j=0..7)

// ---------------------------------------------------------------------------
// K1: pack rnn_in = [emb(x[b]) | ctxv[b]]  (K=1024) and h0[b]  (K=512)
// ---------------------------------------------------------------------------
__global__ void k_embed_pack(const int* __restrict__ x, const float* __restrict__ ctxv,
                             const float* __restrict__ emb, const float* __restrict__ h0,
                             uint4* __restrict__ apk_rnn, uint4* __restrict__ apk_h0) {
    __shared__ float buf[1024];
    __shared__ float hbuf[512];
    const int b = blockIdx.x, t = threadIdx.x;
    const int row = x[b];
    if (t < 128) {
        ((float4*)buf)[t]  = ((const float4*)(emb + (size_t)row * EMBED))[t];
        ((float4*)hbuf)[t] = ((const float4*)(h0 + (size_t)b * HID))[t];
    } else {
        ((float4*)buf)[t] = ((const float4*)(ctxv + (size_t)b * HID))[t - 128];
    }
    __syncthreads();
    const int mt = b >> 4, lb = b & 15;
    if (t < 128) {                       // rnn frag t (K=1024)
        int kc = t >> 4, ksl = (t >> 2) & 3, kg = t & 3;
        apk_rnn[((kc * 8 + mt) * 4 + ksl) * 64 + kg * 16 + lb] = pk8(&buf[t * 8]);
    } else if (t < 192) {                // h0 frag (K=512)
        int i = t - 128;
        int kc = i >> 4, ksl = (i >> 2) & 3, kg = i & 3;
        apk_h0[((kc * 8 + mt) * 4 + ksl) * 64 + kg * 16 + lb] = pk8(&hbuf[i * 8]);
    }
}

// ---------------------------------------------------------------------------
// K2a: MERGED gi/gh GEMM (both N=1536): blocks [0,96) gi (K=1024),
// blocks [96,192) gh (K=512). 4-wave k-split, runtime K.
// ---------------------------------------------------------------------------
__global__ __launch_bounds__(256, 2) void k_gemm2(
        const uint4* __restrict__ apkA, const float* __restrict__ WA,
        const float* __restrict__ bA, float* __restrict__ CA, int KA,
        const uint4* __restrict__ apkB, const float* __restrict__ WB,
        const float* __restrict__ bB, float* __restrict__ CB, int KB,
        int nblkA) {
    const bool isB = (int)blockIdx.x >= nblkA;
    const uint4* apk = isB ? apkB : apkA;
    const float* W   = isB ? WB : WA;
    const float* bias= isB ? bB : bA;
    float* C         = isB ? CB : CA;
    const int K      = isB ? KB : KA;
    const int bid    = isB ? (int)blockIdx.x - nblkA : (int)blockIdx.x;
    const int N = 1536;
    __shared__ float red[4][128][16];          // 32KB
    const int tid = threadIdx.x, lane = tid & 63, wv = tid >> 6;
    const int n0 = bid * 16;
    const int ncol = n0 + (lane & 15);         // < 1536 always
    const int kg = lane >> 4;
    const int spw = K >> 7;                    // slices per wave (8 or 4)
    f32x4 acc[8];
#pragma unroll
    for (int mt = 0; mt < 8; ++mt) acc[mt] = (f32x4)0.f;
    const float4* W4 = (const float4*)W;
    const size_t wb = (size_t)ncol * (K >> 2) + kg * 2;
    for (int s = 0; s < spw; ++s) {
        const int ks = wv * spw + s;
        float4 w0 = W4[wb + ks * 8];
        float4 w1 = W4[wb + ks * 8 + 1];
        short8 bf = __builtin_bit_cast(short8, pk8v(w0, w1));
        const uint4* ap = apk + ((size_t)(ks >> 2) * 32 + (ks & 3)) * 64 + lane;
#pragma unroll
        for (int mt = 0; mt < 8; ++mt) {
            short8 af = __builtin_bit_cast(short8, ap[mt * 256]);
            acc[mt] = __builtin_amdgcn_mfma_f32_16x16x32_bf16(af, bf, acc[mt], 0, 0, 0);
        }
    }
#pragma unroll
    for (int mt = 0; mt < 8; ++mt)
#pragma unroll
        for (int j = 0; j < 4; ++j)
            red[wv][mt * 16 + kg * 4 + j][lane & 15] = acc[mt][j];
    __syncthreads();
#pragma unroll
    for (int i = 0; i < 8; ++i) {
        int o = tid + i * 256;
        int r = o >> 4, c = o & 15;
        float v = red[0][r][c] + red[1][r][c] + red[2][r][c] + red[3][r][c];
        v += bias[n0 + c];
        C[(size_t)r * N + n0 + c] = v;
    }
}

// ---------------------------------------------------------------------------
// K2b: 4-wave k-split MFMA GEMM (Wa / Wc), compile-time config.
// ---------------------------------------------------------------------------
template <int N, int K, int ACT, int HASB, int PACK>
__global__ __launch_bounds__(256, 2) void k_gemm_ks(
        const uint4* __restrict__ apk, const float* __restrict__ W,
        const float* __restrict__ bias, float* __restrict__ C,
        uint4* __restrict__ apk_out) {
    __shared__ float red[4][128][16];          // 32KB
    const int tid = threadIdx.x, lane = tid & 63, wv = tid >> 6;
    const int n0 = blockIdx.x * 16;
    const int ncol = n0 + (lane & 15);
    const int nc = ncol < N ? ncol : N - 1;
    const int kg = lane >> 4;
    constexpr int SPW = K / 128;               // slices per wave (4 or 8)
    f32x4 acc[8];
#pragma unroll
    for (int mt = 0; mt < 8; ++mt) acc[mt] = (f32x4)0.f;
    const float4* W4 = (const float4*)W;
    const size_t wb = (size_t)nc * (K / 4) + kg * 2;
#pragma unroll
    for (int s = 0; s < SPW; ++s) {
        const int ks = wv * SPW + s;
        float4 w0 = W4[wb + ks * 8];
        float4 w1 = W4[wb + ks * 8 + 1];
        short8 bf = __builtin_bit_cast(short8, pk8v(w0, w1));
        const uint4* ap = apk + (((ks >> 2) * 8) * 4 + (ks & 3)) * 64 + lane;
#pragma unroll
        for (int mt = 0; mt < 8; ++mt) {
            short8 af = __builtin_bit_cast(short8, ap[mt * 256]);
            acc[mt] = __builtin_amdgcn_mfma_f32_16x16x32_bf16(af, bf, acc[mt], 0, 0, 0);
        }
    }
#pragma unroll
    for (int mt = 0; mt < 8; ++mt)
#pragma unroll
        for (int j = 0; j < 4; ++j)
            red[wv][mt * 16 + kg * 4 + j][lane & 15] = acc[mt][j];
    __syncthreads();
#pragma unroll
    for (int i = 0; i < 8; ++i) {
        int o = tid + i * 256;
        int r = o >> 4, c = o & 15;
        float v = red[0][r][c] + red[1][r][c] + red[2][r][c] + red[3][r][c];
        if (HASB) v += bias[n0 + c];
        if (ACT) v = tanhf(v);
        C[(size_t)r * N + n0 + c] = v;
        if (PACK) red[0][r][c] = v;            // own (r,c) slot only
    }
    if constexpr (PACK) {
        __syncthreads();
        int r = tid >> 1, hf = tid & 1;        // 256 frags
        float tmp[8];
#pragma unroll
        for (int z = 0; z < 8; ++z) tmp[z] = red[0][r][hf * 8 + z];
        int k0 = n0 + hf * 8;
        int kc = k0 >> 7, ksl = (k0 >> 5) & 3, kg2 = (k0 >> 3) & 3;
        apk_out[((kc * 8 + (r >> 4)) * 4 + ksl) * 64 + kg2 * 16 + (r & 15)] = pk8(tmp);
    }
}

// ---------------------------------------------------------------------------
// K3: GRU gate combine (r,z,n) + pack h fragments (K=512)
// ---------------------------------------------------------------------------
__global__ void k_gru(const float* __restrict__ gi, const float* __restrict__ gh,
                      const float* __restrict__ h0, float* __restrict__ h,
                      uint4* __restrict__ apk_h) {
    __shared__ float hsh[256];
    const int t = threadIdx.x;
    const int idx = blockIdx.x * 256 + t;
    const int b = blockIdx.x >> 1, half = blockIdx.x & 1;
    const int j = half * 256 + t;
    const float* gib = gi + (size_t)b * 1536;
    const float* ghb = gh + (size_t)b * 1536;
    float ir = gib[j], iz = gib[512 + j], inn = gib[1024 + j];
    float hr = ghb[j], hz = ghb[512 + j], hn = ghb[1024 + j];
    float r = 1.f / (1.f + expf(-(ir + hr)));
    float z = 1.f / (1.f + expf(-(iz + hz)));
    float nn = tanhf(inn + r * hn);
    float hv = (1.f - z) * nn + z * h0[idx];
    h[idx] = hv;
    hsh[t] = hv;
    __syncthreads();
    if (t < 32) {
        int k0 = half * 256 + t * 8;
        int kc = k0 >> 7, ksl = (k0 >> 5) & 3, kg = (k0 >> 3) & 3;
        apk_h[((kc * 8 + (b >> 4)) * 4 + ksl) * 64 + kg * 16 + (b & 15)] = pk8(&hsh[t * 8]);
    }
}

// ---------------------------------------------------------------------------
// K4: attention (512 threads)
// ---------------------------------------------------------------------------
__global__ __launch_bounds__(512) void k_attn(const float* __restrict__ enc,
        const float* __restrict__ q, const int* __restrict__ lens,
        const float* __restrict__ h, float* __restrict__ a_out,
        uint4* __restrict__ apk_cat) {
    __shared__ float qs[512];
    __shared__ float red[128];
    __shared__ float aw[128];
    __shared__ float catsh[1024];
    const int b = blockIdx.x, t = threadIdx.x;
    qs[t] = q[(size_t)b * 512 + t];
    __syncthreads();
    const int srow = t >> 2, part = t & 3;
    const float* ep = enc + ((size_t)b * SRC + srow) * 512 + part * 128;
    float s = 0.f;
#pragma unroll
    for (int k4 = 0; k4 < 32; ++k4) {
        float4 e = ((const float4*)ep)[k4];
        float4 qq = *(const float4*)&qs[part * 128 + k4 * 4];
        s = fmaf(e.x, qq.x, fmaf(e.y, qq.y, fmaf(e.z, qq.z, fmaf(e.w, qq.w, s))));
    }
    s += __shfl_xor(s, 1);
    s += __shfl_xor(s, 2);
    if (part == 0) {
        int len = lens[b];
        float val = (srow < len) ? s : 0.f;
        if (val == 0.f) val = -1e10f;   // replicate ref's where(masked==0,-1e10)
        red[srow] = val;
        aw[srow] = val;
    }
    __syncthreads();
    for (int off = 64; off > 0; off >>= 1) {          // max tree
        if (t < off) red[t] = fmaxf(red[t], red[t + off]);
        __syncthreads();
    }
    float mx = red[0];
    __syncthreads();
    if (t < 128) { float e = expf(aw[t] - mx); aw[t] = e; red[t] = e; }
    __syncthreads();
    for (int off = 64; off > 0; off >>= 1) {          // sum tree
        if (t < off) red[t] += red[t + off];
        __syncthreads();
    }
    float denom = red[0];
    if (t < 128) {
        float av = aw[t] / denom;
        aw[t] = av;
        a_out[(size_t)t * B + b] = av;                // layout [S][B]
    }
    __syncthreads();
    float a0 = 0.f;
    const float* e2 = enc + (size_t)b * (SRC * 512) + t;
#pragma unroll 4
    for (int s2 = 0; s2 < SRC; ++s2) a0 = fmaf(aw[s2], e2[(size_t)s2 * 512], a0);
    catsh[t] = a0;
    catsh[512 + t] = h[(size_t)b * 512 + t];
    __syncthreads();
    if (t < 128) {                                    // pack cat frag (K=1024)
        int kc = t >> 4, ksl = (t >> 2) & 3, kg = t & 3;
        apk_cat[((kc * 8 + (b >> 4)) * 4 + ksl) * 64 + kg * 16 + (b & 15)] =
            pk8(&catsh[t * 8]);
    }
}

// ---------------------------------------------------------------------------
// K5: fc1 deep-pipeline direct GEMM. 3142 blocks x 1 wave; wave owns 16 cols
// x all 128 m x full K=512. The ENTIRE per-wave W slice (32 float4 = 128
// VGPR) is hoisted as one burst; __launch_bounds__(64,2) allows 256 VGPR so
// it stays in registers. Consumption in issue order -> counted vmcnt.
// A-fragments stream from L2 (apk 128KB hot). Fused per-block LSE partials.
// ---------------------------------------------------------------------------
__global__ __launch_bounds__(64, 2) void k_fc1e(
        const uint4* __restrict__ apk, const float* __restrict__ W,
        const float* __restrict__ bias, float* __restrict__ C,
        float2* __restrict__ pout, int nblk) {
    const int lane = threadIdx.x;
    const int kg = lane >> 4;
    const int c0 = blockIdx.x * 16 + (lane & 15);
    const int nc0 = c0 < VOCAB ? c0 : VOCAB - 1;
    const float4* W4 = (const float4*)W;
    const size_t wb = (size_t)nc0 * 128 + kg * 2;

    float4 wf[32];                       // full K=512 W slice for own col
#pragma unroll
    for (int ks = 0; ks < 16; ++ks) {    // 32-load burst, all in flight
        wf[2 * ks]     = W4[wb + ks * 8];
        wf[2 * ks + 1] = W4[wb + ks * 8 + 1];
    }
    f32x4 acc[8];
#pragma unroll
    for (int mt = 0; mt < 8; ++mt) acc[mt] = (f32x4)0.f;
#pragma unroll
    for (int ks = 0; ks < 16; ++ks) {
        short8 bf = __builtin_bit_cast(short8, pk8v(wf[2 * ks], wf[2 * ks + 1]));
        const uint4* ap = apk + ((size_t)(ks >> 2) * 32 + (ks & 3)) * 64 + lane;
#pragma unroll
        for (int mt = 0; mt < 8; ++mt) {
            short8 af = __builtin_bit_cast(short8, ap[mt * 256]);
            acc[mt] = __builtin_amdgcn_mfma_f32_16x16x32_bf16(af, bf, acc[mt], 0, 0, 0);
        }
    }
    const float bb = bias[nc0];
#pragma unroll
    for (int mt = 0; mt < 8; ++mt) {
#pragma unroll
        for (int j = 0; j < 4; ++j) {
            const int row = mt * 16 + kg * 4 + j;
            float v = acc[mt][j] + bb;
            if (c0 < VOCAB) C[(size_t)row * VOCAB + c0] = v;
            if (pout) {
                float va = c0 < VOCAB ? v : -1e30f;
                float m = va;
                m = fmaxf(m, __shfl_xor(m, 1));
                m = fmaxf(m, __shfl_xor(m, 2));
                m = fmaxf(m, __shfl_xor(m, 4));
                m = fmaxf(m, __shfl_xor(m, 8));
                float e = c0 < VOCAB ? __expf(va - m) : 0.f;
                e += __shfl_xor(e, 1);
                e += __shfl_xor(e, 2);
                e += __shfl_xor(e, 4);
                e += __shfl_xor(e, 8);
                if ((lane & 15) == 0)
                    pout[(size_t)row * nblk + blockIdx.x] = make_float2(m, e);
            }
        }
    }
}

// ---------------------------------------------------------------------------
// K6a: merge per-block LSE partials -> L[row]
// ---------------------------------------------------------------------------
__global__ __launch_bounds__(256) void k_lse_final(const float2* __restrict__ pout,
                                                   float* __restrict__ L, int nblk) {
    const int row = blockIdx.x, t = threadIdx.x;
    float m = -1e30f, s = 0.f;
    for (int i = t; i < nblk; i += 256) {
        float2 p = pout[(size_t)row * nblk + i];
        float mm = fmaxf(m, p.x);
        s = s * __expf(m - mm) + p.y * __expf(p.x - mm);
        m = mm;
    }
    __shared__ float sm[256], ss[256];
    sm[t] = m; ss[t] = s; __syncthreads();
    for (int off = 128; off > 0; off >>= 1) {
        if (t < off) {
            float m2 = sm[t + off], s2 = ss[t + off];
            float mm = fmaxf(sm[t], m2);
            ss[t] = ss[t] * __expf(sm[t] - mm) + s2 * __expf(m2 - mm);
            sm[t] = mm;
        }
        __syncthreads();
    }
    if (t == 0) L[row] = sm[0] + logf(ss[0]);
}

// ---------------------------------------------------------------------------
// K6b: log_probs = logits - L[b]  (in place), full-machine grid
// ---------------------------------------------------------------------------
__global__ __launch_bounds__(512) void k_lsub(float* __restrict__ logits,
                                              const float* __restrict__ L) {
    const int b = blockIdx.y;
    const float l = L[b];
    float* row = logits + (size_t)b * VOCAB;
    int c0 = (blockIdx.x * 512 + threadIdx.x) * 4;
    if (c0 + 4 <= VOCAB) {
        float4 x = *(float4*)(row + c0);
        x.x -= l; x.y -= l; x.z -= l; x.w -= l;
        *(float4*)(row + c0) = x;
    } else {
        for (int c = c0; c < VOCAB; ++c) row[c] -= l;
    }
}

// ---------------------------------------------------------------------------
// K6-fallback: fused log-softmax (online LSE + in-place subtract)
// ---------------------------------------------------------------------------
__global__ __launch_bounds__(1024) void k_lse_sub(float* __restrict__ logits) {
    const int b = blockIdx.x, t = threadIdx.x;
    float* row = logits + (size_t)b * VOCAB;
    const int N4 = VOCAB >> 2;
    float m = -1e30f, s = 0.f;
    for (int i = t; i < N4; i += 1024) {
        float4 x = ((const float4*)row)[i];
        float xs[4] = {x.x, x.y, x.z, x.w};
#pragma unroll
        for (int j = 0; j < 4; ++j) {
            float v = xs[j];
            if (v > m) { s = s * __expf(m - v) + 1.f; m = v; }
            else        s += __expf(v - m);
        }
    }
    if (t == 0) {
        float v = row[VOCAB - 1];
        if (v > m) { s = s * __expf(m - v) + 1.f; m = v; }
        else        s += __expf(v - m);
    }
    __shared__ float sm[1024], ss[1024];
    sm[t] = m; ss[t] = s;
    __syncthreads();
    for (int off = 512; off > 0; off >>= 1) {
        if (t < off) {
            float m2 = sm[t + off], s2 = ss[t + off];
            float mm = fmaxf(sm[t], m2);
            ss[t] = ss[t] * __expf(sm[t] - mm) + s2 * __expf(m2 - mm);
            sm[t] = mm;
        }
        __syncthreads();
    }
    __shared__ float Lsh;
    if (t == 0) Lsh = sm[0] + logf(ss[0]);
    __syncthreads();
    float L = Lsh;
    for (int i = t; i < N4; i += 1024) {
        float4 x = ((const float4*)row)[i];
        x.x -= L; x.y -= L; x.z -= L; x.w -= L;
        ((float4*)row)[i] = x;
    }
    if (t == 0) row[VOCAB - 1] -= L;
}

// ---------------------------------------------------------------------------
extern "C" void kernel_launch(void* const* d_in, const int* in_sizes, int n_in,
                              void* d_out, int out_size, void* d_ws, size_t ws_size,
                              hipStream_t stream) {
    const int*   x    = (const int*)d_in[0];
    const float* h0   = (const float*)d_in[1];   // decoder_hidden [1,B,H]
    const int*   lens = (const int*)d_in[2];
    const float* enc  = (const float*)d_in[3];   // [B,SRC,H]
    const float* ctxv = (const float*)d_in[4];   // [B,H]
    const float* emb  = (const float*)d_in[5];   // [V,E]
    const float* wih  = (const float*)d_in[6];   // [1536,1024]
    const float* whh  = (const float*)d_in[7];   // [1536,512]
    const float* bih  = (const float*)d_in[8];
    const float* bhh  = (const float*)d_in[9];
    const float* Wa   = (const float*)d_in[10];  // [512,512]
    const float* Wc   = (const float*)d_in[11];  // [512,1024]
    const float* fc1w = (const float*)d_in[12];  // [V,512]
    const float* fc1b = (const float*)d_in[13];

    float* out     = (float*)d_out;
    float* outLogp = out;                                  // [B][VOCAB]
    float* outHid  = out + (size_t)B * VOCAB;              // [B][HID]
    float* outA    = outHid + (size_t)B * HID;             // [SRC][B]
    float* outCtx  = outA + (size_t)SRC * B;               // [B][HID]

    // scratch inside the not-yet-written log_probs region (6.43M floats)
    float* gi = outLogp;                                   // [B][1536]
    float* gh = gi + B * 1536;                             // [B][1536]
    float* q  = gh + B * 1536;                             // [B][512]
    uint4* apk_rnn = (uint4*)(q + B * HID);                // 16384 u4 (K=1024)
    uint4* apk_h0  = apk_rnn + 16384;                      // 8192  u4 (K=512)
    uint4* apk_h   = apk_h0 + 8192;                        // 8192  u4 (K=512)
    uint4* apk_cat = apk_h + 8192;                         // 16384 u4 (K=1024)

    uint4*  apk_ctx = (uint4*)d_ws;                        // 128KB (survives fc1)
    size_t  off_pout = 131072;
    size_t  off_L    = off_pout + (size_t)B * FBLK2 * sizeof(float2);
    bool bigws = ws_size >= off_L + 512;
    float2* pout = bigws ? (float2*)((char*)d_ws + off_pout) : nullptr;
    float*  Lb   = bigws ? (float*)((char*)d_ws + off_L) : nullptr;

    k_embed_pack<<<dim3(B), dim3(256), 0, stream>>>(x, ctxv, emb, h0, apk_rnn, apk_h0);
    k_gemm2<<<dim3(192), dim3(256), 0, stream>>>(
        apk_rnn, wih, bih, gi, 1024,
        apk_h0, whh, bhh, gh, 512, 96);
    k_gru<<<dim3(256), dim3(256), 0, stream>>>(gi, gh, h0, outHid, apk_h);
    k_gemm_ks<512, 512, 0, 0, 0><<<dim3(32), dim3(256), 0, stream>>>(
        apk_h, Wa, nullptr, q, nullptr);
    k_attn<<<dim3(B), dim3(512), 0, stream>>>(enc, q, lens, outHid, outA, apk_cat);
    k_gemm_ks<512, 1024, 1, 0, 1><<<dim3(32), dim3(256), 0, stream>>>(
        apk_cat, Wc, nullptr, outCtx, apk_ctx);
    k_fc1e<<<dim3(FBLK2), dim3(64), 0, stream>>>(apk_ctx, fc1w, fc1b, outLogp,
                                                 pout, FBLK2);
    if (bigws) {
        k_lse_final<<<dim3(B), dim3(256), 0, stream>>>(pout, Lb, FBLK2);
        k_lsub<<<dim3(25, B), dim3(512), 0, stream>>>(outLogp, Lb);
    } else {
        k_lse_sub<<<dim3(B), dim3(1024), 0, stream>>>(outLogp);
    }
}